// Round 13
// baseline (374.691 us; speedup 1.0000x reference)
//
#include <hip/hip_runtime.h>
#include <hip/hip_bf16.h>

// CustomTransformerBlock: B=4,S=2048,D=1024,H=16,DH=64,W=1024,DFF=4096
#define BB 4
#define SS 2048
#define DD 1024
#define HH 16
#define DHH 64
#define WW 1024
#define DFF 4096
#define MM (BB*SS)
#define NEGV (-1e10f)
// K pre-scale: log2(e)/sqrt(1024) folded into K at KV-GEMM epilogue
#define KSC 0.045084220027780106f

using f32x4 = __attribute__((ext_vector_type(4))) float;
using s16x8 = __attribute__((ext_vector_type(8))) short;
using s16x4 = __attribute__((ext_vector_type(4))) short;
using u64 = unsigned long long;

typedef const __attribute__((address_space(1))) void* gas_t;
typedef __attribute__((address_space(3))) void* las_t;

__device__ inline short f2b(float f) {
  __hip_bfloat16 h = __float2bfloat16(f);
  return __builtin_bit_cast(short, h);
}
__device__ inline float b2f(short u) {
  __hip_bfloat16 h = __builtin_bit_cast(__hip_bfloat16, u);
  return __bfloat162float(h);
}

__device__ inline void gload_lds16(const short* g, short* lds) {
  __builtin_amdgcn_global_load_lds((gas_t)g, (las_t)lds, 16, 0, 0);
}

__device__ inline f32x4 mfma16(s16x8 a, s16x8 b, f32x4 c) {
  return __builtin_amdgcn_mfma_f32_16x16x32_bf16(a, b, c, 0, 0, 0);
}

// -------------------- LayerNorm (row of 1024), out bf16 --------------------
template<int IN_BF16>
__global__ __launch_bounds__(256) void ln_kernel(const void* __restrict__ inp,
                                                 const float* __restrict__ g,
                                                 const float* __restrict__ bta,
                                                 short* __restrict__ outp) {
  int row = blockIdx.x;
  int t = threadIdx.x;
  float v[4];
  if constexpr (IN_BF16) {
    s16x4 r4 = *((const s16x4*)((const short*)inp + (size_t)row*DD) + t);
    v[0]=b2f(r4[0]); v[1]=b2f(r4[1]); v[2]=b2f(r4[2]); v[3]=b2f(r4[3]);
  } else {
    f32x4 r4 = *((const f32x4*)((const float*)inp + (size_t)row*DD) + t);
    v[0]=r4[0]; v[1]=r4[1]; v[2]=r4[2]; v[3]=r4[3];
  }
  float s = v[0]+v[1]+v[2]+v[3];
  float sq = v[0]*v[0]+v[1]*v[1]+v[2]*v[2]+v[3]*v[3];
  for (int m=1;m<64;m<<=1){ s += __shfl_xor(s,m); sq += __shfl_xor(sq,m); }
  __shared__ float red[8];
  int wv = t>>6;
  if ((t&63)==0){ red[wv]=s; red[4+wv]=sq; }
  __syncthreads();
  s  = red[0]+red[1]+red[2]+red[3];
  sq = red[4]+red[5]+red[6]+red[7];
  float mean = s*(1.f/DD);
  float rstd = rsqrtf(sq*(1.f/DD) - mean*mean + 1e-5f);
  int col = t*4;
  s16x4 o;
  #pragma unroll
  for (int j=0;j<4;++j) o[j] = f2b((v[j]-mean)*rstd*g[col+j]+bta[col+j]);
  *((s16x4*)(outp + (size_t)row*DD) + t) = o;
}

// ------------- fp32 [K][N] -> bf16 [N][K] transpose-cast (weights) ----------
__global__ __launch_bounds__(256) void transpose_cast(const float* __restrict__ in,
                                                      short* __restrict__ out,
                                                      int K, int N) {
  __shared__ float tile[32][33];
  int n0 = blockIdx.x*32, k0 = blockIdx.y*32;
  int tx = threadIdx.x & 31, ty = threadIdx.x >> 5;
  #pragma unroll
  for (int j=0;j<4;++j) tile[ty+8*j][tx] = in[(size_t)(k0+ty+8*j)*N + n0+tx];
  __syncthreads();
  #pragma unroll
  for (int j=0;j<4;++j) out[(size_t)(n0+ty+8*j)*K + k0+tx] = f2b(tile[tx][ty+8*j]);
}

// ---- pad bool(int) -> per-(b,col16) u64 bitmask: bit(c*4+nf) = pad[c*64+nf*16+col16]
__global__ void pad_bitmask(const int* __restrict__ pad, u64* __restrict__ pm) {
  int idx = threadIdx.x;            // 64 threads: b(2b) x col16(4b)
  int b_ = idx>>4, col = idx&15;
  const int* pb = pad + b_*SS + (SS-WW);
  u64 m = 0;
  for (int c=0;c<16;++c)
    for (int nf=0;nf<4;++nf)
      if (pb[c*64+nf*16+col]) m |= (1ull << (c*4+nf));
  pm[idx] = m;
}

// ---------- 256x256 8-wave GEMM, BK=32, 3-buffer 1-barrier/K-tile ----------
// R13: phase t = {ds_read 12 frags from buf t%3; stage tile t+2 -> buf
// (t+2)%3 (4 loads); 32 MFMA; vmcnt(4) [tile t+1 landed]; s_barrier}.
// Safety: stage into buf X at phase t follows bar(t-1); all waves' reads of
// buf X (tile t-1) complete before their phase-(t-1) MFMAs (lgkmcnt) which
// precede bar(t-1). Wave drift <= 1 phase. Barriers/K-tile: 4 -> 1.
template<int EPI>
__global__ __launch_bounds__(512) void gemm256(const short* __restrict__ A,
                                               const short* __restrict__ Bt,
                                               const float* __restrict__ bias,
                                               void* __restrict__ out1,
                                               int N, int K, int lgx) {
  __shared__ short lds[49152];   // 96KB: 3 bufs x [A 16KB | B 16KB]
  int tid = threadIdx.x, l = tid&63, wid = tid>>6;
  int wm = wid>>2, wn = wid&3;
  int q8 = gridDim.x >> 3;
  int wg = (blockIdx.x & 7)*q8 + (blockIdx.x >> 3);
  int bx = wg & ((1<<lgx)-1), by = wg >> lgx;
  const short* Ablk = A + (size_t)by*256*K;
  const short* Bblk = Bt + (size_t)bx*256*K;
  int rA = l & 15;
  int slot_s = ((l>>4) ^ ((rA>>1)&3))*8;
  int aBase = (wm*128 + rA)*32 + slot_s;
  int bBase = (wn*64  + rA)*32 + slot_s + 8192;
  int qs = (tid&3) ^ ((tid>>3)&3);
  const short* srcA = Ablk + (size_t)(tid>>2)*K + qs*8;
  const short* srcB = Bblk + (size_t)(tid>>2)*K + qs*8;
  int dst0 = (tid & ~63)*8;
  int nt = K >> 5;
  f32x4 acc[8][4];
  #pragma unroll
  for (int i=0;i<8;++i)
    #pragma unroll
    for (int j=0;j<4;++j)
      #pragma unroll
      for (int r=0;r<4;++r) acc[i][j][r]=0.f;

  auto stage = [&](int rgn, int t) {   // 4 loads: A(2) + B(2)
    short* dA = &lds[rgn*16384 + dst0];
    gload_lds16(srcA + t*32,                 dA);
    gload_lds16(srcA + (size_t)128*K + t*32, dA + 4096);
    short* dB = &lds[rgn*16384 + 8192 + dst0];
    gload_lds16(srcB + t*32,                 dB);
    gload_lds16(srcB + (size_t)128*K + t*32, dB + 4096);
  };

  // prologue: tile0 -> buf0, tile1 -> buf1; buf0 complete (buf1 in flight)
  stage(0,0); stage(1,1);
  asm volatile("s_waitcnt vmcnt(4)" ::: "memory");
  __builtin_amdgcn_s_barrier();

  int cur = 0, nx = 2;
  for (int t = 0; t < nt; ++t) {
    int ts = t+2; if (ts >= nt) ts -= nt;   // tail stages wrap (never read)
    s16x8 af[8], bf[4];
    #pragma unroll
    for (int j=0;j<4;++j) bf[j] = *(const s16x8*)&lds[cur*16384 + bBase + j*512];
    #pragma unroll
    for (int j=0;j<8;++j) af[j] = *(const s16x8*)&lds[cur*16384 + aBase + j*512];
    stage(nx, ts);
    __builtin_amdgcn_s_setprio(1);
    #pragma unroll
    for (int j=0;j<8;++j)
      #pragma unroll
      for (int nf=0;nf<4;++nf)
        acc[j][nf] = mfma16(af[j], bf[nf], acc[j][nf]);
    __builtin_amdgcn_s_setprio(0);
    asm volatile("s_waitcnt vmcnt(4)" ::: "memory");   // tile t+1 landed
    __builtin_amdgcn_s_barrier();
    cur = (cur+1==3) ? 0 : cur+1;
    nx  = (nx+1==3)  ? 0 : nx+1;
  }
  asm volatile("s_waitcnt vmcnt(0)" ::: "memory");

  #pragma unroll
  for (int mf=0;mf<8;++mf) {
    #pragma unroll
    for (int nf=0;nf<4;++nf) {
      #pragma unroll
      for (int r=0;r<4;++r) {
        int row = by*256 + wm*128 + mf*16 + ((l>>4)<<2) + r;
        int col = bx*256 + wn*64 + nf*16 + rA;
        float v = acc[mf][nf][r] + bias[col];
        if constexpr (EPI==2) {
          float sv = v / (1.f + __expf(-v));
          ((short*)out1)[(size_t)row*N + col] = f2b(sv);
        } else {
          ((short*)out1)[(size_t)row*N + col] = f2b(v);
        }
      }
    }
  }
}

// ---------- 256x128 8-wave GEMM, BK=32, 3-buffer 1-barrier/K-tile ----------
// Same schedule as gemm256; 3 loads/tile (A2+B1), vmcnt(3), 72KB LDS
// (2 blocks/CU). EPI: 0=q(bf16), 1=kv(K*KSC + V transposed), 3=ff2(f32+resid)
template<int EPI>
__global__ __launch_bounds__(512) void gemm256x128(const short* __restrict__ A,
                                                   const short* __restrict__ Bt,
                                                   const float* __restrict__ bias,
                                                   void* __restrict__ out1,
                                                   void* __restrict__ out2,
                                                   const float* __restrict__ resid,
                                                   int N, int K, int lgx) {
  __shared__ short lds[36864];   // 72KB: 3 bufs x [A 16KB | B 8KB]
  int tid = threadIdx.x, l = tid&63, wid = tid>>6;
  int wm = wid>>1, wn = wid&1;
  int q8 = gridDim.x >> 3;
  int wg = (blockIdx.x & 7)*q8 + (blockIdx.x >> 3);
  int bx = wg & ((1<<lgx)-1), by = wg >> lgx;
  const short* Ablk;
  if constexpr (EPI==1) {
    int b_ = (by*256)>>10, w0 = (by*256)&1023;
    Ablk = A + ((size_t)b_*SS + (SS-WW) + w0)*DD;
  } else {
    Ablk = A + (size_t)by*256*K;
  }
  const short* Bblk = Bt + (size_t)bx*128*K;
  int rA = l & 15;
  int slot_s = ((l>>4) ^ ((rA>>1)&3))*8;
  int aBase = (wm*64 + rA)*32 + slot_s;
  int bBase = 8192 + (wn*64 + rA)*32 + slot_s;
  int qs = (tid&3) ^ ((tid>>3)&3);
  const short* srcA = Ablk + (size_t)(tid>>2)*K + qs*8;
  const short* srcB = Bblk + (size_t)(tid>>2)*K + qs*8;
  int dst0 = (tid & ~63)*8;
  int nt = K >> 5;
  f32x4 acc[4][4];
  #pragma unroll
  for (int i=0;i<4;++i)
    #pragma unroll
    for (int j=0;j<4;++j)
      #pragma unroll
      for (int r=0;r<4;++r) acc[i][j][r]=0.f;

  auto stage = [&](int rgn, int t) {   // 3 loads: A(2) + B(1)
    short* dA = &lds[rgn*12288 + dst0];
    gload_lds16(srcA + t*32,                 dA);
    gload_lds16(srcA + (size_t)128*K + t*32, dA + 4096);
    gload_lds16(srcB + t*32, &lds[rgn*12288 + 8192 + dst0]);
  };

  stage(0,0); stage(1,1);
  asm volatile("s_waitcnt vmcnt(3)" ::: "memory");
  __builtin_amdgcn_s_barrier();

  int cur = 0, nx = 2;
  for (int t = 0; t < nt; ++t) {
    int ts = t+2; if (ts >= nt) ts -= nt;
    s16x8 af[4], bf[4];
    #pragma unroll
    for (int j=0;j<4;++j) bf[j] = *(const s16x8*)&lds[cur*12288 + bBase + j*512];
    #pragma unroll
    for (int j=0;j<4;++j) af[j] = *(const s16x8*)&lds[cur*12288 + aBase + j*512];
    stage(nx, ts);
    __builtin_amdgcn_s_setprio(1);
    #pragma unroll
    for (int j=0;j<4;++j)
      #pragma unroll
      for (int nf=0;nf<4;++nf)
        acc[j][nf] = mfma16(af[j], bf[nf], acc[j][nf]);
    __builtin_amdgcn_s_setprio(0);
    asm volatile("s_waitcnt vmcnt(3)" ::: "memory");
    __builtin_amdgcn_s_barrier();
    cur = (cur+1==3) ? 0 : cur+1;
    nx  = (nx+1==3)  ? 0 : nx+1;
  }
  asm volatile("s_waitcnt vmcnt(0)" ::: "memory");

  #pragma unroll
  for (int mf=0;mf<4;++mf) {
    #pragma unroll
    for (int nf=0;nf<4;++nf) {
      #pragma unroll
      for (int r=0;r<4;++r) {
        int row = by*256 + wm*64 + mf*16 + ((l>>4)<<2) + r;
        int col = bx*128 + wn*64 + nf*16 + rA;
        float v = acc[mf][nf][r] + bias[col];
        if constexpr (EPI==0) {
          ((short*)out1)[(size_t)row*N + col] = f2b(v);
        } else if constexpr (EPI==1) {
          int b_ = row>>10, w_ = row&1023;
          if (col < DD) {
            int h = col>>6, dh = col&63;
            ((short*)out1)[(((size_t)(b_*HH+h))*WW + w_)*DHH + dh] = f2b(v*KSC);
          } else {
            int cc = col - DD;
            int h = cc>>6, dh = cc&63;
            ((short*)out2)[(((size_t)(b_*HH+h))*DHH + dh)*WW + w_] = f2b(v);
          }
        } else {
          ((float*)out1)[(size_t)row*N + col] = v + resid[(size_t)row*N + col];
        }
      }
    }
  }
}

// -------------------- Flash attention over W=1024 keys --------------------
// R8-exact (best measured: ~127us, VGPR 116, no spill). 1 wave per workgroup,
// 32 q-rows/wave, 4096 blocks, no barriers. K/V L2-resident; log2-domain
// scores (K pre-scaled by KSC) -> exp2; defer-max; early V issue.
struct KF { s16x8 v[4][2]; };

__global__ __launch_bounds__(64,2) void attn_kernel(const short* __restrict__ q,
    const short* __restrict__ kpan, const short* __restrict__ vtpan,
    const u64* __restrict__ pmarr, short* __restrict__ outp) {
  __shared__ short P[32*72];
  int l = threadIdx.x;
  int id = blockIdx.x;
  int xcd = id & 7, slot = id >> 3;
  int bh = xcd + 8*(slot >> 6);        // 0..63 (= b*16+h)
  int u  = 63 - (slot & 63);           // 32-row tile, heavy-first
  int bb = bh >> 4, h = bh & 15;
  int r0 = u*32;
  const short* kbase = kpan + (size_t)bh*WW*DHH;
  const short* vbase = vtpan + (size_t)bh*DHH*WW;
  u64 pmask = pmarr[bb*16 + (l&15)];
  const s16x8 ones8 = { 0x3F80,0x3F80,0x3F80,0x3F80,0x3F80,0x3F80,0x3F80,0x3F80 };

  s16x8 aq[2][2];
  #pragma unroll
  for (int g=0;g<2;++g)
    #pragma unroll
    for (int kf=0;kf<2;++kf)
      aq[g][kf] = *(const s16x8*)(q + ((size_t)bb*SS + r0 + g*16 + (l&15))*DD
                                    + h*DHH + (l>>4)*8 + kf*32);
  f32x4 oacc[2][4];
  float mrun[2][4], lrun[2][4], scale[2][4];
  #pragma unroll
  for (int g=0;g<2;++g)
    #pragma unroll
    for (int i=0;i<4;++i) {
      #pragma unroll
      for (int r=0;r<4;++r) oacc[g][i][r]=0.f;
      mrun[g][i]=-INFINITY; lrun[g][i]=0.f;
    }
  int dchunk = u>>1;
  int nch = dchunk+1 < 16 ? dchunk+1 : 16;

  auto loadK = [&](int c, KF& d) {
    const short* kc = kbase + (size_t)c*64*DHH;
    #pragma unroll
    for (int nf=0;nf<4;++nf) {
      const short* p = kc + (size_t)(nf*16+(l&15))*DHH + ((l>>4)*8);
      d.v[nf][0] = *(const s16x8*)p;
      d.v[nf][1] = *(const s16x8*)(p+32);
    }
  };

  auto body = [&](int c, KF& kf) {
    f32x4 sc[2][4];
    #pragma unroll
    for (int g=0;g<2;++g)
      #pragma unroll
      for (int nf=0;nf<4;++nf)
        #pragma unroll
        for (int r=0;r<4;++r) sc[g][nf][r]=0.f;
    __builtin_amdgcn_s_setprio(1);
    #pragma unroll
    for (int nf=0;nf<4;++nf)
      #pragma unroll
      for (int g=0;g<2;++g) {
        sc[g][nf] = mfma16(aq[g][0], kf.v[nf][0], sc[g][nf]);
        sc[g][nf] = mfma16(aq[g][1], kf.v[nf][1], sc[g][nf]);
      }
    __builtin_amdgcn_s_setprio(0);
    unsigned nib = (unsigned)(pmask >> (c*4)) & 15u;
    float pm[2][4];
    #pragma unroll
    for (int g=0;g<2;++g)
      #pragma unroll
      for (int r=0;r<4;++r) pm[g][r] = -INFINITY;
    if (c >= dchunk) {               // diagonal / future: pad + causal
      #pragma unroll
      for (int nf=0;nf<4;++nf) {
        int j = c*64 + nf*16 + (l&15);
        int padj = (int)((nib>>nf)&1u);
        #pragma unroll
        for (int g=0;g<2;++g)
          #pragma unroll
          for (int r=0;r<4;++r) {
            int sq_ = r0 + g*16 + ((l>>4)<<2) + r;
            float xv = (padj || (j > sq_)) ? NEGV : sc[g][nf][r];
            sc[g][nf][r] = xv;
            pm[g][r] = fmaxf(pm[g][r], xv);
          }
      }
    } else {                          // interior: pad-only
      #pragma unroll
      for (int nf=0;nf<4;++nf) {
        int padj = (int)((nib>>nf)&1u);
        #pragma unroll
        for (int g=0;g<2;++g)
          #pragma unroll
          for (int r=0;r<4;++r) {
            float xv = padj ? NEGV : sc[g][nf][r];
            sc[g][nf][r] = xv;
            pm[g][r] = fmaxf(pm[g][r], xv);
          }
      }
    }
    s16x8 vf0[4], vf1[4];
    #pragma unroll
    for (int nf=0;nf<4;++nf)
      vf0[nf] = *(const s16x8*)(vbase + (size_t)(nf*16+(l&15))*WW
                                + c*64 + ((l>>4)*8));
    int need = 0;
    #pragma unroll
    for (int g=0;g<2;++g)
      #pragma unroll
      for (int r=0;r<4;++r) need |= (pm[g][r] > mrun[g][r] + 12.f) ? 1 : 0;
    #pragma unroll
    for (int g=0;g<2;++g)
      #pragma unroll
      for (int r=0;r<4;++r) scale[g][r] = 1.f;
    if (__any(need)) {
      #pragma unroll
      for (int m=1;m<16;m<<=1)
        #pragma unroll
        for (int g=0;g<2;++g)
          #pragma unroll
          for (int r=0;r<4;++r) pm[g][r] = fmaxf(pm[g][r], __shfl_xor(pm[g][r], m));
      #pragma unroll
      for (int g=0;g<2;++g)
        #pragma unroll
        for (int r=0;r<4;++r) {
          float mn = fmaxf(mrun[g][r], pm[g][r]);
          scale[g][r] = exp2f(mrun[g][r]-mn);
          mrun[g][r] = mn;
        }
      #pragma unroll
      for (int g=0;g<2;++g)
        #pragma unroll
        for (int nf=0;nf<4;++nf)
          #pragma unroll
          for (int r=0;r<4;++r) oacc[g][nf][r] *= scale[g][r];
    }
    #pragma unroll
    for (int nf=0;nf<4;++nf)
      #pragma unroll
      for (int g=0;g<2;++g)
        #pragma unroll
        for (int r=0;r<4;++r)
          sc[g][nf][r] = exp2f(sc[g][nf][r]-mrun[g][r]);
    #pragma unroll
    for (int nf=0;nf<4;++nf)
      vf1[nf] = *(const s16x8*)(vbase + (size_t)(nf*16+(l&15))*WW
                                + c*64 + 32 + ((l>>4)*8));
    #pragma unroll
    for (int g=0;g<2;++g)
      #pragma unroll
      for (int nf=0;nf<4;++nf)
        #pragma unroll
        for (int r=0;r<4;++r)
          P[(g*16+((l>>4)<<2)+r)*72 + nf*16 + (l&15)] = f2b(sc[g][nf][r]);
    f32x4 ls2[2];
    #pragma unroll
    for (int g=0;g<2;++g)
      #pragma unroll
      for (int r=0;r<4;++r) ls2[g][r]=0.f;
    __builtin_amdgcn_s_setprio(1);
    #pragma unroll
    for (int ks=0;ks<2;++ks) {
      s16x8 ap[2];
      #pragma unroll
      for (int g=0;g<2;++g) {
        ap[g] = *(const s16x8*)&P[(g*16+(l&15))*72 + ks*32 + ((l>>4)*8)];
        ls2[g] = mfma16(ap[g], ones8, ls2[g]);
      }
      #pragma unroll
      for (int nf=0;nf<4;++nf) {
        s16x8 bv = ks ? vf1[nf] : vf0[nf];
        #pragma unroll
        for (int g=0;g<2;++g)
          oacc[g][nf] = mfma16(ap[g], bv, oacc[g][nf]);
      }
    }
    __builtin_amdgcn_s_setprio(0);
    #pragma unroll
    for (int g=0;g<2;++g)
      #pragma unroll
      for (int r=0;r<4;++r) lrun[g][r] = lrun[g][r]*scale[g][r] + ls2[g][r];
  };

  KF ka, kb;
  loadK(0, ka);
  int cend = nch, c = 0, ext = 0;
  while (true) {
    if (c == cend) {
      if (ext) break;
      ext = 1;
      int dead = 0;
      #pragma unroll
      for (int g=0;g<2;++g)
        #pragma unroll
        for (int r=0;r<4;++r) dead |= (mrun[g][r] < -5e9f) ? 1 : 0;
      if (!__any(dead)) break;
      cend = 16;
      if (c >= 16) break;
    }
    if (c+1 < 16) loadK(c+1, kb);   // prefetch next chunk's K (L2-hit)
    body(c, ka);
    ka = kb;
    ++c;
  }

  #pragma unroll
  for (int g=0;g<2;++g)
    #pragma unroll
    for (int nf=0;nf<4;++nf)
      #pragma unroll
      for (int r=0;r<4;++r) {
        int srow = r0 + g*16 + ((l>>4)<<2) + r;
        float o = oacc[g][nf][r] / lrun[g][r];
        outp[((size_t)bb*SS + srow)*DD + h*DHH + nf*16 + (l&15)] = f2b(o);
      }
}

// -------------------- driver --------------------
extern "C" void kernel_launch(void* const* d_in, const int* in_sizes, int n_in,
                              void* d_out, int out_size, void* d_ws, size_t ws_size,
                              hipStream_t stream) {
  const float* x    = (const float*)d_in[0];
  const int*   pad  = (const int*)d_in[1];   // bool mask as int32 on device
  const float* ln1g = (const float*)d_in[2];
  const float* ln1b = (const float*)d_in[3];
  const float* wq   = (const float*)d_in[4];
  const float* bq   = (const float*)d_in[5];
  const float* wkv  = (const float*)d_in[6];
  const float* bkv  = (const float*)d_in[7];
  const float* ln2g = (const float*)d_in[8];
  const float* ln2b = (const float*)d_in[9];
  const float* w1   = (const float*)d_in[10];
  const float* b1   = (const float*)d_in[11];
  const float* w2   = (const float*)d_in[12];
  const float* b2   = (const float*)d_in[13];

  char* ws = (char*)d_ws;
  const size_t MB = 1024*1024;
  short* ln1x = (short*)(ws + 0);        // 16MB, dead after KV gemm
  short* qb   = (short*)(ws + 16*MB);    // 16MB, dead after attn
  short* kpan = (short*)(ws + 32*MB);    //  8MB, dead after attn
  short* vtp  = (short*)(ws + 40*MB);    //  8MB, dead after attn
  u64*   pmar = (u64*)  (ws + 48*MB);    //  512B
  short* h1   = (short*)(ws + 0);        // 64MB, reuses [0,64MB) after attn
  short* outb = (short*)(ws + 64*MB);    // 16MB attn out
  short* hb   = (short*)(ws + 80*MB);    // 16MB ln2 out
  short* wqT  = (short*)(ws + 96*MB);    //  2MB
  short* wkvT = (short*)(ws + 98*MB);    //  4MB
  short* w1T  = (short*)(ws + 102*MB);   //  8MB
  short* w2T  = (short*)(ws + 110*MB);   //  8MB  (total 118MB)

  pad_bitmask<<<1,64,0,stream>>>(pad, pmar);
  transpose_cast<<<dim3(32,32),  256,0,stream>>>(wq,  wqT,  1024, 1024);
  transpose_cast<<<dim3(64,32),  256,0,stream>>>(wkv, wkvT, 1024, 2048);
  transpose_cast<<<dim3(128,32), 256,0,stream>>>(w1,  w1T,  1024, 4096);
  transpose_cast<<<dim3(32,128), 256,0,stream>>>(w2,  w2T,  4096, 1024);
  ln_kernel<0><<<MM,256,0,stream>>>(x, ln1g, ln1b, ln1x);
  gemm256x128<0><<<256,512,0,stream>>>(ln1x, wqT,  bq,  qb,   nullptr, nullptr, 1024, 1024, 3);
  gemm256x128<1><<<256,512,0,stream>>>(ln1x, wkvT, bkv, kpan, vtp,     nullptr, 2048, 1024, 4);
  attn_kernel<<<4096,64,0,stream>>>(qb, kpan, vtp, pmar, outb);
  ln_kernel<1><<<MM,256,0,stream>>>(outb, ln2g, ln2b, hb);
  gemm256<2><<<512,512,0,stream>>>(hb, w1T, b1, h1, 4096, 1024, 4);
  gemm256x128<3><<<256,512,0,stream>>>(h1, w2T, b2, d_out, nullptr, x, 1024, 4096, 3);
}

// Round 14
// 366.781 us; speedup vs baseline: 1.0216x; 1.0216x over previous
//
#include <hip/hip_runtime.h>
#include <hip/hip_bf16.h>

// CustomTransformerBlock: B=4,S=2048,D=1024,H=16,DH=64,W=1024,DFF=4096
#define BB 4
#define SS 2048
#define DD 1024
#define HH 16
#define DHH 64
#define WW 1024
#define DFF 4096
#define MM (BB*SS)
#define NEGV (-1e10f)
// K pre-scale: log2(e)/sqrt(1024) folded into K at KV-GEMM epilogue
#define KSC 0.045084220027780106f

using f32x4 = __attribute__((ext_vector_type(4))) float;
using s16x8 = __attribute__((ext_vector_type(8))) short;
using s16x4 = __attribute__((ext_vector_type(4))) short;
using u64 = unsigned long long;

typedef const __attribute__((address_space(1))) void* gas_t;
typedef __attribute__((address_space(3))) void* las_t;

__device__ inline short f2b(float f) {
  __hip_bfloat16 h = __float2bfloat16(f);
  return __builtin_bit_cast(short, h);
}
__device__ inline float b2f(short u) {
  __hip_bfloat16 h = __builtin_bit_cast(__hip_bfloat16, u);
  return __bfloat162float(h);
}

__device__ inline void gload_lds16(const short* g, short* lds) {
  __builtin_amdgcn_global_load_lds((gas_t)g, (las_t)lds, 16, 0, 0);
}

__device__ inline f32x4 mfma16(s16x8 a, s16x8 b, f32x4 c) {
  return __builtin_amdgcn_mfma_f32_16x16x32_bf16(a, b, c, 0, 0, 0);
}

// -------------------- LayerNorm (row of 1024), out bf16 --------------------
template<int IN_BF16>
__global__ __launch_bounds__(256) void ln_kernel(const void* __restrict__ inp,
                                                 const float* __restrict__ g,
                                                 const float* __restrict__ bta,
                                                 short* __restrict__ outp) {
  int row = blockIdx.x;
  int t = threadIdx.x;
  float v[4];
  if constexpr (IN_BF16) {
    s16x4 r4 = *((const s16x4*)((const short*)inp + (size_t)row*DD) + t);
    v[0]=b2f(r4[0]); v[1]=b2f(r4[1]); v[2]=b2f(r4[2]); v[3]=b2f(r4[3]);
  } else {
    f32x4 r4 = *((const f32x4*)((const float*)inp + (size_t)row*DD) + t);
    v[0]=r4[0]; v[1]=r4[1]; v[2]=r4[2]; v[3]=r4[3];
  }
  float s = v[0]+v[1]+v[2]+v[3];
  float sq = v[0]*v[0]+v[1]*v[1]+v[2]*v[2]+v[3]*v[3];
  for (int m=1;m<64;m<<=1){ s += __shfl_xor(s,m); sq += __shfl_xor(sq,m); }
  __shared__ float red[8];
  int wv = t>>6;
  if ((t&63)==0){ red[wv]=s; red[4+wv]=sq; }
  __syncthreads();
  s  = red[0]+red[1]+red[2]+red[3];
  sq = red[4]+red[5]+red[6]+red[7];
  float mean = s*(1.f/DD);
  float rstd = rsqrtf(sq*(1.f/DD) - mean*mean + 1e-5f);
  int col = t*4;
  s16x4 o;
  #pragma unroll
  for (int j=0;j<4;++j) o[j] = f2b((v[j]-mean)*rstd*g[col+j]+bta[col+j]);
  *((s16x4*)(outp + (size_t)row*DD) + t) = o;
}

// ------------- fp32 [K][N] -> bf16 [N][K] transpose-cast (weights) ----------
__global__ __launch_bounds__(256) void transpose_cast(const float* __restrict__ in,
                                                      short* __restrict__ out,
                                                      int K, int N) {
  __shared__ float tile[32][33];
  int n0 = blockIdx.x*32, k0 = blockIdx.y*32;
  int tx = threadIdx.x & 31, ty = threadIdx.x >> 5;
  #pragma unroll
  for (int j=0;j<4;++j) tile[ty+8*j][tx] = in[(size_t)(k0+ty+8*j)*N + n0+tx];
  __syncthreads();
  #pragma unroll
  for (int j=0;j<4;++j) out[(size_t)(n0+ty+8*j)*K + k0+tx] = f2b(tile[tx][ty+8*j]);
}

// ---- pad bool(int) -> per-(b,col16) u64 bitmask: bit(c*4+nf) = pad[c*64+nf*16+col16]
__global__ void pad_bitmask(const int* __restrict__ pad, u64* __restrict__ pm) {
  int idx = threadIdx.x;            // 64 threads: b(2b) x col16(4b)
  int b_ = idx>>4, col = idx&15;
  const int* pb = pad + b_*SS + (SS-WW);
  u64 m = 0;
  for (int c=0;c<16;++c)
    for (int nf=0;nf<4;++nf)
      if (pb[c*64+nf*16+col]) m |= (1ull << (c*4+nf));
  pm[idx] = m;
}

// ---------- 256x256 8-wave GEMM, BK=32, 4-phase counted-vmcnt schedule ------
// R8-exact (best measured for FF1: ~95us). R13's 1-barrier/K-tile variant
// regressed (fine interleave is the lever). Regions A0|B0|A1|B1, 64KB LDS.
template<int EPI>
__global__ __launch_bounds__(512) void gemm256(const short* __restrict__ A,
                                               const short* __restrict__ Bt,
                                               const float* __restrict__ bias,
                                               void* __restrict__ out1,
                                               int N, int K, int lgx) {
  __shared__ short lds[32768];   // 64KB
  int tid = threadIdx.x, l = tid&63, wid = tid>>6;
  int wm = wid>>2, wn = wid&3;
  int q8 = gridDim.x >> 3;
  int wg = (blockIdx.x & 7)*q8 + (blockIdx.x >> 3);
  int bx = wg & ((1<<lgx)-1), by = wg >> lgx;
  const short* Ablk = A + (size_t)by*256*K;
  const short* Bblk = Bt + (size_t)bx*256*K;
  int rA = l & 15;
  int slot_s = ((l>>4) ^ ((rA>>1)&3))*8;
  int aBase = (wm*128 + rA)*32 + slot_s;
  int bBase = (wn*64  + rA)*32 + slot_s + 8192;
  int qs = (tid&3) ^ ((tid>>3)&3);
  const short* srcA = Ablk + (size_t)(tid>>2)*K + qs*8;
  const short* srcB = Bblk + (size_t)(tid>>2)*K + qs*8;
  int dst0 = (tid & ~63)*8;
  int nt = K >> 5;
  f32x4 acc[8][4];
  #pragma unroll
  for (int i=0;i<8;++i)
    #pragma unroll
    for (int j=0;j<4;++j)
      #pragma unroll
      for (int r=0;r<4;++r) acc[i][j][r]=0.f;

  auto stage = [&](int isB, int b, int t) {
    const short* s = isB ? srcB : srcA;
    short* d = &lds[b*16384 + isB*8192 + dst0];
    gload_lds16(s + t*32,                 d);
    gload_lds16(s + (size_t)128*K + t*32, d + 4096);
  };
  s16x8 af[4], bf[4];
  auto readA = [&](int b, int mg) {
    #pragma unroll
    for (int j=0;j<4;++j) af[j] = *(const s16x8*)&lds[b*16384 + aBase + (mg*4+j)*512];
  };
  auto readB = [&](int b) {
    #pragma unroll
    for (int j=0;j<4;++j) bf[j] = *(const s16x8*)&lds[b*16384 + bBase + j*512];
  };
  auto mfmas = [&](int mg) {
    __builtin_amdgcn_s_setprio(1);
    #pragma unroll
    for (int j=0;j<4;++j)
      #pragma unroll
      for (int nf=0;nf<4;++nf)
        acc[mg*4+j][nf] = mfma16(af[j], bf[nf], acc[mg*4+j][nf]);
    __builtin_amdgcn_s_setprio(0);
  };

  stage(0,0,0); stage(1,0,0); stage(1,1,1);
  asm volatile("s_waitcnt vmcnt(2)" ::: "memory");
  __builtin_amdgcn_s_barrier();

  for (int it = 0; it < (nt>>1); ++it) {
    int t0 = 2*it;
    int t2 = t0+2; if (t2 >= nt) t2 -= nt;
    int t3 = t0+3; if (t3 >= nt) t3 -= nt;
    readB(0); readA(0,0);
    stage(0,1,t0+1);
    __builtin_amdgcn_s_barrier();
    mfmas(0);
    __builtin_amdgcn_s_barrier();
    readA(0,1);
    stage(1,0,t2);
    __builtin_amdgcn_s_barrier();
    mfmas(1);
    asm volatile("s_waitcnt vmcnt(2)" ::: "memory");
    __builtin_amdgcn_s_barrier();
    readB(1); readA(1,0);
    stage(0,0,t2);
    __builtin_amdgcn_s_barrier();
    mfmas(0);
    __builtin_amdgcn_s_barrier();
    readA(1,1);
    stage(1,1,t3);
    __builtin_amdgcn_s_barrier();
    mfmas(1);
    asm volatile("s_waitcnt vmcnt(2)" ::: "memory");
    __builtin_amdgcn_s_barrier();
  }
  asm volatile("s_waitcnt vmcnt(0)" ::: "memory");

  #pragma unroll
  for (int mf=0;mf<8;++mf) {
    #pragma unroll
    for (int nf=0;nf<4;++nf) {
      #pragma unroll
      for (int r=0;r<4;++r) {
        int row = by*256 + wm*128 + mf*16 + ((l>>4)<<2) + r;
        int col = bx*256 + wn*64 + nf*16 + rA;
        float v = acc[mf][nf][r] + bias[col];
        if constexpr (EPI==2) {
          float sv = v / (1.f + __expf(-v));
          ((short*)out1)[(size_t)row*N + col] = f2b(sv);
        } else {
          ((short*)out1)[(size_t)row*N + col] = f2b(v);
        }
      }
    }
  }
}

// ---------- 256x128 8-wave GEMM, BK=32, 4-phase counted-vmcnt schedule ------
// (R8-exact). EPI: 0=q(bf16), 1=kv(K*KSC + V transposed), 3=ff2(f32 +resid)
template<int EPI>
__global__ __launch_bounds__(512) void gemm256x128(const short* __restrict__ A,
                                                   const short* __restrict__ Bt,
                                                   const float* __restrict__ bias,
                                                   void* __restrict__ out1,
                                                   void* __restrict__ out2,
                                                   const float* __restrict__ resid,
                                                   int N, int K, int lgx) {
  __shared__ short lds[24576];   // 48KB: [A0 16KB][B0 8KB][A1 16KB][B1 8KB]
  int tid = threadIdx.x, l = tid&63, wid = tid>>6;
  int wm = wid>>1, wn = wid&1;
  int q8 = gridDim.x >> 3;
  int wg = (blockIdx.x & 7)*q8 + (blockIdx.x >> 3);
  int bx = wg & ((1<<lgx)-1), by = wg >> lgx;
  const short* Ablk;
  if constexpr (EPI==1) {
    int b_ = (by*256)>>10, w0 = (by*256)&1023;
    Ablk = A + ((size_t)b_*SS + (SS-WW) + w0)*DD;
  } else {
    Ablk = A + (size_t)by*256*K;
  }
  const short* Bblk = Bt + (size_t)bx*128*K;
  int rA = l & 15;
  int slot_s = ((l>>4) ^ ((rA>>1)&3))*8;
  int aBase = (wm*64 + rA)*32 + slot_s;
  int bBase = 8192 + (wn*64 + rA)*32 + slot_s;
  int qs = (tid&3) ^ ((tid>>3)&3);
  const short* srcA = Ablk + (size_t)(tid>>2)*K + qs*8;
  const short* srcB = Bblk + (size_t)(tid>>2)*K + qs*8;
  int dst0 = (tid & ~63)*8;
  int nt = K >> 5;
  f32x4 acc[4][4];
  #pragma unroll
  for (int i=0;i<4;++i)
    #pragma unroll
    for (int j=0;j<4;++j)
      #pragma unroll
      for (int r=0;r<4;++r) acc[i][j][r]=0.f;

  auto stageA = [&](int b, int t) {
    short* d = &lds[b*12288 + dst0];
    gload_lds16(srcA + t*32,                 d);
    gload_lds16(srcA + (size_t)128*K + t*32, d + 4096);
  };
  auto stageB = [&](int b, int t) {
    gload_lds16(srcB + t*32, &lds[b*12288 + 8192 + dst0]);
  };
  s16x8 af[2], bf[4];
  auto readA = [&](int b, int mg) {
    #pragma unroll
    for (int j=0;j<2;++j) af[j] = *(const s16x8*)&lds[b*12288 + aBase + (mg*2+j)*512];
  };
  auto readB = [&](int b) {
    #pragma unroll
    for (int j=0;j<4;++j) bf[j] = *(const s16x8*)&lds[b*12288 + bBase + j*512];
  };
  auto mfmas = [&](int mg) {
    __builtin_amdgcn_s_setprio(1);
    #pragma unroll
    for (int j=0;j<2;++j)
      #pragma unroll
      for (int nf=0;nf<4;++nf)
        acc[mg*2+j][nf] = mfma16(af[j], bf[nf], acc[mg*2+j][nf]);
    __builtin_amdgcn_s_setprio(0);
  };

  stageA(0,0); stageB(0,0); stageB(1,1);
  asm volatile("s_waitcnt vmcnt(1)" ::: "memory");
  __builtin_amdgcn_s_barrier();

  for (int it = 0; it < (nt>>1); ++it) {
    int t0 = 2*it;
    int t2 = t0+2; if (t2 >= nt) t2 -= nt;
    int t3 = t0+3; if (t3 >= nt) t3 -= nt;
    readB(0); readA(0,0);
    stageA(1,t0+1);
    __builtin_amdgcn_s_barrier();
    mfmas(0);
    __builtin_amdgcn_s_barrier();
    readA(0,1);
    stageB(0,t2);
    __builtin_amdgcn_s_barrier();
    mfmas(1);
    asm volatile("s_waitcnt vmcnt(1)" ::: "memory");
    __builtin_amdgcn_s_barrier();
    readB(1); readA(1,0);
    stageA(0,t2);
    __builtin_amdgcn_s_barrier();
    mfmas(0);
    __builtin_amdgcn_s_barrier();
    readA(1,1);
    stageB(1,t3);
    __builtin_amdgcn_s_barrier();
    mfmas(1);
    asm volatile("s_waitcnt vmcnt(1)" ::: "memory");
    __builtin_amdgcn_s_barrier();
  }
  asm volatile("s_waitcnt vmcnt(0)" ::: "memory");

  #pragma unroll
  for (int mf=0;mf<4;++mf) {
    #pragma unroll
    for (int nf=0;nf<4;++nf) {
      #pragma unroll
      for (int r=0;r<4;++r) {
        int row = by*256 + wm*64 + mf*16 + ((l>>4)<<2) + r;
        int col = bx*128 + wn*64 + nf*16 + rA;
        float v = acc[mf][nf][r] + bias[col];
        if constexpr (EPI==0) {
          ((short*)out1)[(size_t)row*N + col] = f2b(v);
        } else if constexpr (EPI==1) {
          int b_ = row>>10, w_ = row&1023;
          if (col < DD) {
            int h = col>>6, dh = col&63;
            ((short*)out1)[(((size_t)(b_*HH+h))*WW + w_)*DHH + dh] = f2b(v*KSC);
          } else {
            int cc = col - DD;
            int h = cc>>6, dh = cc&63;
            ((short*)out2)[(((size_t)(b_*HH+h))*DHH + dh)*WW + w_] = f2b(v);
          }
        } else {
          ((float*)out1)[(size_t)row*N + col] = v + resid[(size_t)row*N + col];
        }
      }
    }
  }
}

// -------------------- Flash attention over W=1024 keys --------------------
// R14: R8 body with PV LAGGED ONE CHUNK (register-neutral pipeline).
// iter c: {issue V(c-1) loads -> QK(c) MFMA -> PV(c-1) from P_lds[(c-1)&1]
//          -> softmax(c) -> P-write[c&1]}. Removes the P-roundtrip + PV tail
// from the per-chunk chain; QK latency hides under PV. Only new state:
// scp (scale of previous chunk, 8 VGPR) + P double-buffer in LDS.
struct KF { s16x8 v[4][2]; };

__global__ __launch_bounds__(64,2) void attn_kernel(const short* __restrict__ q,
    const short* __restrict__ kpan, const short* __restrict__ vtpan,
    const u64* __restrict__ pmarr, short* __restrict__ outp) {
  __shared__ short P[2][32*72];
  int l = threadIdx.x;
  int id = blockIdx.x;
  int xcd = id & 7, slot = id >> 3;
  int bh = xcd + 8*(slot >> 6);        // 0..63 (= b*16+h)
  int u  = 63 - (slot & 63);           // 32-row tile, heavy-first
  int bb = bh >> 4, h = bh & 15;
  int r0 = u*32;
  const short* kbase = kpan + (size_t)bh*WW*DHH;
  const short* vbase = vtpan + (size_t)bh*DHH*WW;
  u64 pmask = pmarr[bb*16 + (l&15)];
  const s16x8 ones8 = { 0x3F80,0x3F80,0x3F80,0x3F80,0x3F80,0x3F80,0x3F80,0x3F80 };

  s16x8 aq[2][2];
  #pragma unroll
  for (int g=0;g<2;++g)
    #pragma unroll
    for (int kf=0;kf<2;++kf)
      aq[g][kf] = *(const s16x8*)(q + ((size_t)bb*SS + r0 + g*16 + (l&15))*DD
                                    + h*DHH + (l>>4)*8 + kf*32);
  f32x4 oacc[2][4];
  float mrun[2][4], lrun[2][4], scp[2][4];
  #pragma unroll
  for (int g=0;g<2;++g)
    #pragma unroll
    for (int i=0;i<4;++i) {
      #pragma unroll
      for (int r=0;r<4;++r) oacc[g][i][r]=0.f;
      mrun[g][i]=-INFINITY; lrun[g][i]=0.f; scp[g][i]=1.f;
    }
  int dchunk = u>>1;
  int cend = dchunk+1 < 16 ? dchunk+1 : 16;

  auto loadK = [&](int c, KF& d) {
    const short* kc = kbase + (size_t)c*64*DHH;
    #pragma unroll
    for (int nf=0;nf<4;++nf) {
      const short* p = kc + (size_t)(nf*16+(l&15))*DHH + ((l>>4)*8);
      d.v[nf][0] = *(const s16x8*)p;
      d.v[nf][1] = *(const s16x8*)(p+32);
    }
  };

  f32x4 sc[2][4];

  auto QK = [&](KF& kf) {
    #pragma unroll
    for (int g=0;g<2;++g)
      #pragma unroll
      for (int nf=0;nf<4;++nf)
        #pragma unroll
        for (int r=0;r<4;++r) sc[g][nf][r]=0.f;
    __builtin_amdgcn_s_setprio(1);
    #pragma unroll
    for (int nf=0;nf<4;++nf)
      #pragma unroll
      for (int g=0;g<2;++g) {
        sc[g][nf] = mfma16(aq[g][0], kf.v[nf][0], sc[g][nf]);
        sc[g][nf] = mfma16(aq[g][1], kf.v[nf][1], sc[g][nf]);
      }
    __builtin_amdgcn_s_setprio(0);
  };

  auto loadV = [&](int c, s16x8 (&vf0)[4], s16x8 (&vf1)[4]) {
    #pragma unroll
    for (int nf=0;nf<4;++nf)
      vf0[nf] = *(const s16x8*)(vbase + (size_t)(nf*16+(l&15))*WW
                                + c*64 + ((l>>4)*8));
    #pragma unroll
    for (int nf=0;nf<4;++nf)
      vf1[nf] = *(const s16x8*)(vbase + (size_t)(nf*16+(l&15))*WW
                                + c*64 + 32 + ((l>>4)*8));
  };

  // PV of chunk c: reads P[c&1]; adds into oacc (pre-rescale of chunk c+1);
  // lrun update uses scp = scale(c).
  auto PV = [&](int c, s16x8 (&vf0)[4], s16x8 (&vf1)[4]) {
    f32x4 ls2[2];
    #pragma unroll
    for (int g=0;g<2;++g)
      #pragma unroll
      for (int r=0;r<4;++r) ls2[g][r]=0.f;
    const short* Pb = &P[c&1][0];
    __builtin_amdgcn_s_setprio(1);
    #pragma unroll
    for (int ks=0;ks<2;++ks) {
      s16x8 ap[2];
      #pragma unroll
      for (int g=0;g<2;++g) {
        ap[g] = *(const s16x8*)&Pb[(g*16+(l&15))*72 + ks*32 + ((l>>4)*8)];
        ls2[g] = mfma16(ap[g], ones8, ls2[g]);
      }
      #pragma unroll
      for (int nf=0;nf<4;++nf) {
        s16x8 bv = ks ? vf1[nf] : vf0[nf];
        #pragma unroll
        for (int g=0;g<2;++g)
          oacc[g][nf] = mfma16(ap[g], bv, oacc[g][nf]);
      }
    }
    __builtin_amdgcn_s_setprio(0);
    #pragma unroll
    for (int g=0;g<2;++g)
      #pragma unroll
      for (int r=0;r<4;++r) lrun[g][r] = lrun[g][r]*scp[g][r] + ls2[g][r];
  };

  // softmax of chunk c: mask, defer-max (scale -> scp), exp2, P-write[c&1]
  auto SM = [&](int c) {
    unsigned nib = (unsigned)(pmask >> (c*4)) & 15u;
    float pm[2][4];
    #pragma unroll
    for (int g=0;g<2;++g)
      #pragma unroll
      for (int r=0;r<4;++r) pm[g][r] = -INFINITY;
    if (c >= dchunk) {               // diagonal / future: pad + causal
      #pragma unroll
      for (int nf=0;nf<4;++nf) {
        int j = c*64 + nf*16 + (l&15);
        int padj = (int)((nib>>nf)&1u);
        #pragma unroll
        for (int g=0;g<2;++g)
          #pragma unroll
          for (int r=0;r<4;++r) {
            int sq_ = r0 + g*16 + ((l>>4)<<2) + r;
            float xv = (padj || (j > sq_)) ? NEGV : sc[g][nf][r];
            sc[g][nf][r] = xv;
            pm[g][r] = fmaxf(pm[g][r], xv);
          }
      }
    } else {                          // interior: pad-only
      #pragma unroll
      for (int nf=0;nf<4;++nf) {
        int padj = (int)((nib>>nf)&1u);
        #pragma unroll
        for (int g=0;g<2;++g)
          #pragma unroll
          for (int r=0;r<4;++r) {
            float xv = padj ? NEGV : sc[g][nf][r];
            sc[g][nf][r] = xv;
            pm[g][r] = fmaxf(pm[g][r], xv);
          }
      }
    }
    int need = 0;
    #pragma unroll
    for (int g=0;g<2;++g)
      #pragma unroll
      for (int r=0;r<4;++r) need |= (pm[g][r] > mrun[g][r] + 12.f) ? 1 : 0;
    #pragma unroll
    for (int g=0;g<2;++g)
      #pragma unroll
      for (int r=0;r<4;++r) scp[g][r] = 1.f;
    if (__any(need)) {
      #pragma unroll
      for (int m=1;m<16;m<<=1)
        #pragma unroll
        for (int g=0;g<2;++g)
          #pragma unroll
          for (int r=0;r<4;++r) pm[g][r] = fmaxf(pm[g][r], __shfl_xor(pm[g][r], m));
      #pragma unroll
      for (int g=0;g<2;++g)
        #pragma unroll
        for (int r=0;r<4;++r) {
          float mn = fmaxf(mrun[g][r], pm[g][r]);
          scp[g][r] = exp2f(mrun[g][r]-mn);
          mrun[g][r] = mn;
        }
      #pragma unroll
      for (int g=0;g<2;++g)
        #pragma unroll
        for (int nf=0;nf<4;++nf)
          #pragma unroll
          for (int r=0;r<4;++r) oacc[g][nf][r] *= scp[g][r];
    }
    #pragma unroll
    for (int nf=0;nf<4;++nf)
      #pragma unroll
      for (int g=0;g<2;++g)
        #pragma unroll
        for (int r=0;r<4;++r)
          sc[g][nf][r] = exp2f(sc[g][nf][r]-mrun[g][r]);
    short* Pb = &P[c&1][0];
    #pragma unroll
    for (int g=0;g<2;++g)
      #pragma unroll
      for (int nf=0;nf<4;++nf)
        #pragma unroll
        for (int r=0;r<4;++r)
          Pb[(g*16+((l>>4)<<2)+r)*72 + nf*16 + (l&15)] = f2b(sc[g][nf][r]);
  };

  // ---- main pipeline: PV lags SM by one chunk ----
  KF ka, kb;
  loadK(0, ka);
  int c = 0;
  while (c < cend) {
    if (c+1 < 16) loadK(c+1, kb);
    s16x8 vf0[4], vf1[4];
    if (c > 0) loadV(c-1, vf0, vf1);   // issue early: consumed after QK
    QK(ka);
    if (c > 0) PV(c-1, vf0, vf1);
    SM(c);
    ka = kb;
    ++c;
  }
  {  // drain the last chunk's PV
    s16x8 vf0[4], vf1[4];
    loadV(cend-1, vf0, vf1);
    PV(cend-1, vf0, vf1);
  }

  // fully-padded rows must softmax uniformly over ALL 1024 keys (rare path;
  // flat per-chunk body: QK -> SM -> PV, same semantics as R8)
  int dead = 0;
  #pragma unroll
  for (int g=0;g<2;++g)
    #pragma unroll
    for (int r=0;r<4;++r) dead |= (mrun[g][r] < -5e9f) ? 1 : 0;
  if (__any(dead)) {
    for (int e=cend; e<16; ++e) {
      loadK(e, ka);
      s16x8 vf0[4], vf1[4];
      loadV(e, vf0, vf1);
      QK(ka);
      SM(e);
      PV(e, vf0, vf1);
    }
  }

  #pragma unroll
  for (int g=0;g<2;++g)
    #pragma unroll
    for (int nf=0;nf<4;++nf)
      #pragma unroll
      for (int r=0;r<4;++r) {
        int srow = r0 + g*16 + ((l>>4)<<2) + r;
        float o = oacc[g][nf][r] / lrun[g][r];
        outp[((size_t)bb*SS + srow)*DD + h*DHH + nf*16 + (l&15)] = f2b(o);
      }
}

// -------------------- driver --------------------
extern "C" void kernel_launch(void* const* d_in, const int* in_sizes, int n_in,
                              void* d_out, int out_size, void* d_ws, size_t ws_size,
                              hipStream_t stream) {
  const float* x    = (const float*)d_in[0];
  const int*   pad  = (const int*)d_in[1];   // bool mask as int32 on device
  const float* ln1g = (const float*)d_in[2];
  const float* ln1b = (const float*)d_in[3];
  const float* wq   = (const float*)d_in[4];
  const float* bq   = (const float*)d_in[5];
  const float* wkv  = (const float*)d_in[6];
  const float* bkv  = (const float*)d_in[7];
  const float* ln2g = (const float*)d_in[8];
  const float* ln2b = (const float*)d_in[9];
  const float* w1   = (const float*)d_in[10];
  const float* b1   = (const float*)d_in[11];
  const float* w2   = (const float*)d_in[12];
  const float* b2   = (const float*)d_in[13];

  char* ws = (char*)d_ws;
  const size_t MB = 1024*1024;
  short* ln1x = (short*)(ws + 0);        // 16MB, dead after KV gemm
  short* qb   = (short*)(ws + 16*MB);    // 16MB, dead after attn
  short* kpan = (short*)(ws + 32*MB);    //  8MB, dead after attn
  short* vtp  = (short*)(ws + 40*MB);    //  8MB, dead after attn
  u64*   pmar = (u64*)  (ws + 48*MB);    //  512B
  short* h1   = (short*)(ws + 0);        // 64MB, reuses [0,64MB) after attn
  short* outb = (short*)(ws + 64*MB);    // 16MB attn out
  short* hb   = (short*)(ws + 80*MB);    // 16MB ln2 out
  short* wqT  = (short*)(ws + 96*MB);    //  2MB
  short* wkvT = (short*)(ws + 98*MB);    //  4MB
  short* w1T  = (short*)(ws + 102*MB);   //  8MB
  short* w2T  = (short*)(ws + 110*MB);   //  8MB  (total 118MB)

  pad_bitmask<<<1,64,0,stream>>>(pad, pmar);
  transpose_cast<<<dim3(32,32),  256,0,stream>>>(wq,  wqT,  1024, 1024);
  transpose_cast<<<dim3(64,32),  256,0,stream>>>(wkv, wkvT, 1024, 2048);
  transpose_cast<<<dim3(128,32), 256,0,stream>>>(w1,  w1T,  1024, 4096);
  transpose_cast<<<dim3(32,128), 256,0,stream>>>(w2,  w2T,  4096, 1024);
  ln_kernel<0><<<MM,256,0,stream>>>(x, ln1g, ln1b, ln1x);
  gemm256x128<0><<<256,512,0,stream>>>(ln1x, wqT,  bq,  qb,   nullptr, nullptr, 1024, 1024, 3);
  gemm256x128<1><<<256,512,0,stream>>>(ln1x, wkvT, bkv, kpan, vtp,     nullptr, 2048, 1024, 4);
  attn_kernel<<<4096,64,0,stream>>>(qb, kpan, vtp, pmar, outb);
  ln_kernel<1><<<MM,256,0,stream>>>(outb, ln2g, ln2b, hb);
  gemm256<2><<<512,512,0,stream>>>(hb, w1T, b1, h1, 4096, 1024, 4);
  gemm256x128<3><<<256,512,0,stream>>>(h1, w2T, b2, d_out, nullptr, x, 1024, 4096, 3);
}